// Round 3
// baseline (484.020 us; speedup 1.0000x reference)
//
#include <hip/hip_runtime.h>

// DynamicVoxelizer: B=8, N=1e6, C=4 fp32 points -> 5 concatenated outputs
// (points_out[B,N,4], voxel_coords[B,N,3], point_idxes[B,N],
//  point_offsets[B,N,3], valid[B,N]) written as float values into d_out.
//
// R1/R2: LDS-stage 3-wide/scalar outputs -> all stores lane-contiguous dwordx4.
// R3: NT-store removal — NEUTRAL.
// R4: per-wave ownership, 4x MLP, no __syncthreads — NEUTRAL.
//   All structural variants land at dur_us ~450; per-CU issue arithmetic says
//   each should saturate HBM. Remaining hypotheses: (A) 6 concurrent DRAM
//   address streams per wave cap efficiency at ~2.5 TB/s (fill = 1 stream @
//   6.35 TB/s, copy = 2 streams @ 6.29 TB/s); (B) kernel is already ~100 us
//   and dur_us is dominated by harness poison fill + reset dispatches.
// R5: region-split double dispatch — 3 streams per kernel. A: pts -> po+idx+val
//   (cached loads warm LLC). B: pts (LLC-hot re-read) -> vox+poff. Story A
//   predicts dur_us -> ~340-380; Story B predicts ~455-485 -> declare roofline.

#define NPTS 1000000  // N (points per batch) — fixed by the problem
#define BLK 128       // 2 waves per block
#define WPT 256       // points per wave (4 per lane); block covers 512 pts

typedef float f4 __attribute__((ext_vector_type(4)));

// ---------------------------------------------------------------- kernel A --
// points_out (16B/pt) + point_idxes (4B/pt) + valid (4B/pt); 3 DRAM streams.
__global__ __launch_bounds__(BLK) void voxelize_A(
    const f4* __restrict__ pts, float* __restrict__ out, int total) {
  __shared__ __align__(16) float s_misc[2][WPT * 2];  // idx[256] | val[256]

  const int lane  = threadIdx.x & 63;
  const int wave  = threadIdx.x >> 6;
  const int pbase = blockIdx.x * ((BLK / 64) * WPT) + wave * WPT;

  f4 p[4];
#pragma unroll
  for (int k = 0; k < 4; ++k)
    p[k] = pts[pbase + k * 64 + lane];   // cached: warm LLC for kernel B

  float* sm = s_misc[wave];

#pragma unroll
  for (int k = 0; k < 4; ++k) {
    const int i = pbase + k * 64 + lane;
    f4 q = p[k];
    bool has_nan = (q.x != q.x) | (q.y != q.y) | (q.z != q.z) | (q.w != q.w);

    // cf = floor((xyz - pmin) / vs) — IEEE sub + correctly-rounded div to
    // match numpy op-for-op.
    float fx = floorf((q.x - (-51.2f)) / 0.1f);
    float fy = floorf((q.y - (-51.2f)) / 0.1f);
    float fz = floorf((q.z - (-5.0f))  / 0.2f);
    int cx = (int)fx, cy = (int)fy, cz = (int)fz;

    bool in_range = (cx >= 0) & (cx < 1024) &
                    (cy >= 0) & (cy < 1024) &
                    (cz >= 0) & (cz < 40);
    bool valid = (!has_nan) && in_range;

    f4 po = valid ? q : (f4){0.0f, 0.0f, 0.0f, 0.0f};
    ((f4*)out)[i] = po;

    const int s = k * 64 + lane;
    sm[s]       = valid ? (float)(i % NPTS) : -1.0f;  // arange(N) per batch
    sm[WPT + s] = valid ? 1.0f : 0.0f;
  }

  __builtin_amdgcn_wave_barrier();

  const long long t = total;
  f4* gidx = (f4*)(out + 7  * t) + pbase / 4;   // 64 f4/wave
  f4* gval = (f4*)(out + 11 * t) + pbase / 4;   // 64 f4/wave
  const f4* m4 = (const f4*)sm;
  gidx[lane] = m4[lane];
  gval[lane] = m4[64 + lane];
}

// ---------------------------------------------------------------- kernel B --
// voxel_coords (12B/pt) + point_offsets (12B/pt); input re-read is LLC-hot.
__global__ __launch_bounds__(BLK) void voxelize_B(
    const f4* __restrict__ pts, float* __restrict__ out, int total) {
  __shared__ __align__(16) float s_vox [2][WPT * 3];
  __shared__ __align__(16) float s_poff[2][WPT * 3];

  const int lane  = threadIdx.x & 63;
  const int wave  = threadIdx.x >> 6;
  const int pbase = blockIdx.x * ((BLK / 64) * WPT) + wave * WPT;

  f4 p[4];
#pragma unroll
  for (int k = 0; k < 4; ++k)
    p[k] = pts[pbase + k * 64 + lane];

  float* sv = s_vox[wave];
  float* so = s_poff[wave];

#pragma unroll
  for (int k = 0; k < 4; ++k) {
    f4 q = p[k];
    bool has_nan = (q.x != q.x) | (q.y != q.y) | (q.z != q.z) | (q.w != q.w);

    float fx = floorf((q.x - (-51.2f)) / 0.1f);
    float fy = floorf((q.y - (-51.2f)) / 0.1f);
    float fz = floorf((q.z - (-5.0f))  / 0.2f);
    int cx = (int)fx, cy = (int)fy, cz = (int)fz;

    bool in_range = (cx >= 0) & (cx < 1024) &
                    (cy >= 0) & (cy < 1024) &
                    (cz >= 0) & (cz < 40);
    bool valid = (!has_nan) && in_range;

    float ox = q.x - (fx * 0.1f + (-51.2f) + 0.05f);
    float oy = q.y - (fy * 0.1f + (-51.2f) + 0.05f);
    float oz = q.z - (fz * 0.2f + (-5.0f)  + 0.1f);

    const int s = k * 64 + lane;
    sv[s * 3 + 0] = valid ? (float)cz : -1.0f;  // reversed (z,y,x)
    sv[s * 3 + 1] = valid ? (float)cy : -1.0f;
    sv[s * 3 + 2] = valid ? (float)cx : -1.0f;
    so[s * 3 + 0] = valid ? ox : 0.0f;
    so[s * 3 + 1] = valid ? oy : 0.0f;
    so[s * 3 + 2] = valid ? oz : 0.0f;
  }

  __builtin_amdgcn_wave_barrier();

  const long long t = total;
  f4* gvox  = (f4*)(out + 4 * t) + (long long)pbase * 3 / 4;  // 192 f4/wave
  f4* gpoff = (f4*)(out + 8 * t) + (long long)pbase * 3 / 4;  // 192 f4/wave
  const f4* v4 = (const f4*)sv;
  const f4* o4 = (const f4*)so;
#pragma unroll
  for (int j = 0; j < 3; ++j) gvox[j * 64 + lane] = v4[j * 64 + lane];
#pragma unroll
  for (int j = 0; j < 3; ++j) gpoff[j * 64 + lane] = o4[j * 64 + lane];
}

// Scalar tail path for total % 512 != 0 (unused at B*N = 8e6, kept for safety).
__global__ __launch_bounds__(64) void voxelize_tail(
    const float* __restrict__ ptsf, float* __restrict__ out, int total, int start) {
  int i = start + blockIdx.x * blockDim.x + threadIdx.x;
  if (i >= total) return;
  float px = ptsf[i * 4 + 0], py = ptsf[i * 4 + 1];
  float pz = ptsf[i * 4 + 2], pw = ptsf[i * 4 + 3];
  bool has_nan = (px != px) | (py != py) | (pz != pz) | (pw != pw);
  float fx = floorf((px - (-51.2f)) / 0.1f);
  float fy = floorf((py - (-51.2f)) / 0.1f);
  float fz = floorf((pz - (-5.0f))  / 0.2f);
  int cx = (int)fx, cy = (int)fy, cz = (int)fz;
  bool in_range = (cx >= 0) & (cx < 1024) & (cy >= 0) & (cy < 1024) &
                  (cz >= 0) & (cz < 40);
  bool valid = (!has_nan) && in_range;
  float ox = px - (fx * 0.1f + (-51.2f) + 0.05f);
  float oy = py - (fy * 0.1f + (-51.2f) + 0.05f);
  float oz = pz - (fz * 0.2f + (-5.0f)  + 0.1f);
  long long t = total;
  out[i * 4 + 0] = valid ? px : 0.0f;
  out[i * 4 + 1] = valid ? py : 0.0f;
  out[i * 4 + 2] = valid ? pz : 0.0f;
  out[i * 4 + 3] = valid ? pw : 0.0f;
  float* vox  = out + 4 * t  + (long long)i * 3;
  float* poff = out + 8 * t  + (long long)i * 3;
  if (valid) {
    vox[0] = (float)cz; vox[1] = (float)cy; vox[2] = (float)cx;
    poff[0] = ox; poff[1] = oy; poff[2] = oz;
    out[7 * t + i]  = (float)(i % NPTS);
    out[11 * t + i] = 1.0f;
  } else {
    vox[0] = -1.0f; vox[1] = -1.0f; vox[2] = -1.0f;
    poff[0] = 0.0f; poff[1] = 0.0f; poff[2] = 0.0f;
    out[7 * t + i]  = -1.0f;
    out[11 * t + i] = 0.0f;
  }
}

extern "C" void kernel_launch(void* const* d_in, const int* in_sizes, int n_in,
                              void* d_out, int out_size, void* d_ws, size_t ws_size,
                              hipStream_t stream) {
  (void)n_in; (void)d_ws; (void)ws_size; (void)out_size;
  const f4* pts = (const f4*)d_in[0];
  float* out = (float*)d_out;
  int total = in_sizes[0] / 4;  // B*N = 8,000,000
  const int ppb = (BLK / 64) * WPT;  // 512 points per block
  int full_blocks = total / ppb;     // 15625 exact at 8e6
  if (full_blocks > 0) {
    voxelize_A<<<full_blocks, BLK, 0, stream>>>(pts, out, total);
    voxelize_B<<<full_blocks, BLK, 0, stream>>>(pts, out, total);
  }
  int rem = total - full_blocks * ppb;
  if (rem > 0)
    voxelize_tail<<<(rem + 63) / 64, 64, 0, stream>>>((const float*)d_in[0], out,
                                                      total, full_blocks * ppb);
}

// Round 4
// 445.403 us; speedup vs baseline: 1.0867x; 1.0867x over previous
//
#include <hip/hip_runtime.h>

// DynamicVoxelizer: B=8, N=1e6, C=4 fp32 points -> 5 concatenated outputs
// (points_out[B,N,4], voxel_coords[B,N,3], point_idxes[B,N],
//  point_offsets[B,N,3], valid[B,N]) written as float values into d_out.
//
// R1/R2: stage the 3-wide / scalar outputs through LDS so every global store
//        is a lane-contiguous nontemporal dwordx4.
// R3 (NT->cached stores): NEUTRAL. R4 (per-wave, no-barrier, 4x MLP): NEUTRAL.
// R5 (region-split, 3 streams/kernel): REGRESSED +33us -> proved Story B:
//   the kernel itself is ~100us for 512 MB mandatory traffic (~5+ TB/s,
//   within ~20% of the 6.3 TB/s copy ceiling); dur_us ~450 is dominated by
//   the harness poison fill (~242us @ 79% HBM peak) + reset dispatches.
// R6: revert to the best measured variant (this file). At roofline.

#define NPTS 1000000  // N (points per batch) — fixed by the problem
#define BLK 256

typedef float f4 __attribute__((ext_vector_type(4)));  // NT-builtin-compatible

__global__ __launch_bounds__(BLK) void voxelize_kernel(
    const f4* __restrict__ pts, float* __restrict__ out, int total) {
  __shared__ __align__(16) float s_vox[BLK * 3];   // z,y,x per point
  __shared__ __align__(16) float s_poff[BLK * 3];
  __shared__ __align__(16) float s_misc[BLK * 2];  // idx[256] | val[256]

  const int tid  = threadIdx.x;
  const int base = blockIdx.x * BLK;      // full blocks only (total % 256 == 0)
  const int i    = base + tid;

  f4 p = __builtin_nontemporal_load(&pts[i]);

  bool has_nan = (p.x != p.x) | (p.y != p.y) | (p.z != p.z) | (p.w != p.w);

  // cf = floor((xyz - pmin) / vs) — IEEE sub + correctly-rounded div to match
  // numpy op-for-op (a 1-voxel flip breaks the point_offsets tolerance).
  float fx = floorf((p.x - (-51.2f)) / 0.1f);
  float fy = floorf((p.y - (-51.2f)) / 0.1f);
  float fz = floorf((p.z - (-5.0f))  / 0.2f);
  int cx = (int)fx, cy = (int)fy, cz = (int)fz;

  bool in_range = (cx >= 0) & (cx < 1024) &
                  (cy >= 0) & (cy < 1024) &
                  (cz >= 0) & (cz < 40);
  bool valid = (!has_nan) && in_range;

  float ox = p.x - (fx * 0.1f + (-51.2f) + 0.05f);
  float oy = p.y - (fy * 0.1f + (-51.2f) + 0.05f);
  float oz = p.z - (fz * 0.2f + (-5.0f)  + 0.1f);

  // points_out: already 16B/lane contiguous — store direct.
  f4 po = valid ? p : (f4){0.0f, 0.0f, 0.0f, 0.0f};
  __builtin_nontemporal_store(po, &((f4*)out)[i]);

  // Stage 3-wide + scalar outputs in LDS (stride-3 dword writes = 2-way = free).
  if (valid) {
    s_vox[tid * 3 + 0] = (float)cz;   // reversed (z,y,x)
    s_vox[tid * 3 + 1] = (float)cy;
    s_vox[tid * 3 + 2] = (float)cx;
    s_poff[tid * 3 + 0] = ox;
    s_poff[tid * 3 + 1] = oy;
    s_poff[tid * 3 + 2] = oz;
    s_misc[tid]       = (float)(i % NPTS);  // arange(N) per batch
    s_misc[BLK + tid] = 1.0f;
  } else {
    s_vox[tid * 3 + 0] = -1.0f;
    s_vox[tid * 3 + 1] = -1.0f;
    s_vox[tid * 3 + 2] = -1.0f;
    s_poff[tid * 3 + 0] = 0.0f;
    s_poff[tid * 3 + 1] = 0.0f;
    s_poff[tid * 3 + 2] = 0.0f;
    s_misc[tid]       = -1.0f;
    s_misc[BLK + tid] = 0.0f;
  }
  __syncthreads();

  const long long t = total;
  // Region base offsets (floats): all 16B-aligned for t = 8e6, base % 256 == 0.
  f4* gvox  = (f4*)(out + 4 * t  + (long long)base * 3);  // 192 float4
  f4* gpoff = (f4*)(out + 8 * t  + (long long)base * 3);  // 192 float4
  f4* gidx  = (f4*)(out + 7 * t  + base);                 // 64 float4
  f4* gval  = (f4*)(out + 11 * t + base);                 // 64 float4

  const f4* v4 = (const f4*)s_vox;   // 192 entries, 16B/lane reads
  const f4* o4 = (const f4*)s_poff;
  const f4* m4 = (const f4*)s_misc;  // 128 entries

  if (tid < 192) {
    __builtin_nontemporal_store(v4[tid], &gvox[tid]);
    __builtin_nontemporal_store(o4[tid], &gpoff[tid]);
  } else {
    int j = tid - 192;                       // 64 threads cover idx + val
    __builtin_nontemporal_store(m4[j],      &gidx[j]);
    __builtin_nontemporal_store(m4[64 + j], &gval[j]);
  }
}

// Scalar tail path for total % 256 != 0 (unused at B*N = 8e6, kept for safety).
__global__ __launch_bounds__(64) void voxelize_tail(
    const float* __restrict__ ptsf, float* __restrict__ out, int total, int start) {
  int i = start + blockIdx.x * blockDim.x + threadIdx.x;
  if (i >= total) return;
  float px = ptsf[i * 4 + 0], py = ptsf[i * 4 + 1];
  float pz = ptsf[i * 4 + 2], pw = ptsf[i * 4 + 3];
  bool has_nan = (px != px) | (py != py) | (pz != pz) | (pw != pw);
  float fx = floorf((px - (-51.2f)) / 0.1f);
  float fy = floorf((py - (-51.2f)) / 0.1f);
  float fz = floorf((pz - (-5.0f))  / 0.2f);
  int cx = (int)fx, cy = (int)fy, cz = (int)fz;
  bool in_range = (cx >= 0) & (cx < 1024) & (cy >= 0) & (cy < 1024) &
                  (cz >= 0) & (cz < 40);
  bool valid = (!has_nan) && in_range;
  float ox = px - (fx * 0.1f + (-51.2f) + 0.05f);
  float oy = py - (fy * 0.1f + (-51.2f) + 0.05f);
  float oz = pz - (fz * 0.2f + (-5.0f)  + 0.1f);
  long long t = total;
  out[i * 4 + 0] = valid ? px : 0.0f;
  out[i * 4 + 1] = valid ? py : 0.0f;
  out[i * 4 + 2] = valid ? pz : 0.0f;
  out[i * 4 + 3] = valid ? pw : 0.0f;
  float* vox  = out + 4 * t  + (long long)i * 3;
  float* poff = out + 8 * t  + (long long)i * 3;
  if (valid) {
    vox[0] = (float)cz; vox[1] = (float)cy; vox[2] = (float)cx;
    poff[0] = ox; poff[1] = oy; poff[2] = oz;
    out[7 * t + i]  = (float)(i % NPTS);
    out[11 * t + i] = 1.0f;
  } else {
    vox[0] = -1.0f; vox[1] = -1.0f; vox[2] = -1.0f;
    poff[0] = 0.0f; poff[1] = 0.0f; poff[2] = 0.0f;
    out[7 * t + i]  = -1.0f;
    out[11 * t + i] = 0.0f;
  }
}

extern "C" void kernel_launch(void* const* d_in, const int* in_sizes, int n_in,
                              void* d_out, int out_size, void* d_ws, size_t ws_size,
                              hipStream_t stream) {
  (void)n_in; (void)d_ws; (void)ws_size; (void)out_size;
  const f4* pts = (const f4*)d_in[0];
  float* out = (float*)d_out;
  int total = in_sizes[0] / 4;  // B*N = 8,000,000
  int full_blocks = total / BLK;
  if (full_blocks > 0)
    voxelize_kernel<<<full_blocks, BLK, 0, stream>>>(pts, out, total);
  int rem = total - full_blocks * BLK;
  if (rem > 0)
    voxelize_tail<<<(rem + 63) / 64, 64, 0, stream>>>((const float*)d_in[0], out,
                                                      total, full_blocks * BLK);
}